// Round 3
// baseline (461.234 us; speedup 1.0000x reference)
//
#include <hip/hip_runtime.h>
#include <hip/hip_bf16.h>

// KiloNeRF grouped tiny-MLP dispatch. Inputs AND outputs are float32 (the
// reference is pure jnp.float32; round-1/2 failures pinned the buffer dtypes:
// fp32-as-bf16 reads gave NaN garbage, bf16-packed writes read back as fp32
// gave the decimated absmax=1.1 signature).
//
// 4 points per 256-thread block, one 64-lane wave per point:
//   - lanes cooperatively compute posenc into wave-private LDS
//   - matvecs: lane o=lane&31 owns output o, the two wave halves split the
//     input dim (i = half, half+2, ...) -> each weight-row load is a 128B
//     coalesced read of W[i][0..31]; one shfl_xor(32) combines halves.
//   - sigma / rgb heads via wave shuffle reduction.
// Expert index arithmetic mirrors the reference's float32 op order EXACTLY
// ((p+1.5f)/3.0f, *16, clip, trunc) -- a 1-ulp difference selects a
// different expert's weights and fails absmax.

__device__ __forceinline__ float wave_sum64(float v) {
#pragma unroll
    for (int off = 32; off >= 1; off >>= 1) v += __shfl_xor(v, off, 64);
    return v;
}

// out[o] = bias[o] + sum_i s_in[i] * W[i*32+o], W row-major (n x 32), fp32
__device__ __forceinline__ float halfsum_matvec(const float* __restrict__ s_in, int n,
                                                const float* __restrict__ Wm,
                                                const float* __restrict__ bb,
                                                int lane) {
    const int half = lane >> 5;
    const int o = lane & 31;
    float acc = 0.f;
    for (int i = half; i < n; i += 2)
        acc = fmaf(s_in[i], Wm[i * 32 + o], acc);
    acc += __shfl_xor(acc, 32, 64);
    return acc + bb[o];
}

__global__ __launch_bounds__(256) void kilonerf_kernel(
    const float* __restrict__ pts, const float* __restrict__ viewdirs,
    const float* __restrict__ W1, const float* __restrict__ b1,
    const float* __restrict__ W2, const float* __restrict__ b2,
    const float* __restrict__ Wf, const float* __restrict__ bfc,
    const float* __restrict__ Wsig, const float* __restrict__ bsig,
    const float* __restrict__ Wv, const float* __restrict__ bv,
    const float* __restrict__ Wrgb, const float* __restrict__ brgb,
    float* __restrict__ out_rgb, float* __restrict__ out_sigma,
    int samples) {
    const int wave = threadIdx.x >> 6;
    const int lane = threadIdx.x & 63;
    const int pt = blockIdx.x * 4 + wave;

    __shared__ float s_xp_all[4][63];   // posenc(p)
    __shared__ float s_ha_all[4][32];   // layer1 relu out; reused post-view-layer
    __shared__ float s_hb_all[4][32];   // layer2 relu out
    __shared__ float s_hv_all[4][59];   // [feat(32) | posenc(d)(27)]
    float* s_xp = s_xp_all[wave];
    float* s_ha = s_ha_all[wave];
    float* s_hb = s_hb_all[wave];
    float* s_hv = s_hv_all[wave];

    const float px = pts[3 * pt + 0];
    const float py = pts[3 * pt + 1];
    const float pz = pts[3 * pt + 2];
    const int ray = pt / samples;
    const float dxv = viewdirs[3 * ray + 0];
    const float dyv = viewdirs[3 * ray + 1];
    const float dzv = viewdirs[3 * ray + 2];

    // voxel/expert index -- EXACT float32 op order of the reference
    int ix, iy, iz;
    {
        float nx = (px - (-1.5f)) / 3.0f;
        float ny = (py - (-1.5f)) / 3.0f;
        float nz = (pz - (-1.5f)) / 3.0f;
        float sx = fminf(fmaxf(nx * 16.0f, 0.0f), 15.0f);
        float sy = fminf(fmaxf(ny * 16.0f, 0.0f), 15.0f);
        float sz = fminf(fmaxf(nz * 16.0f, 0.0f), 15.0f);
        ix = (int)sx; iy = (int)sy; iz = (int)sz;
    }
    const int e = ix * 256 + iy * 16 + iz;

    // posenc(p): [x,y,z, then per l: sin(2^l x),sin(2^l y),sin(2^l z),
    //                               cos(2^l x),cos(2^l y),cos(2^l z)]
    if (lane < 63) {
        float v;
        if (lane < 3) {
            v = (lane == 0) ? px : ((lane == 1) ? py : pz);
        } else {
            int k = lane - 3, l = k / 6, r = k % 6;
            float c = ((r % 3) == 0) ? px : (((r % 3) == 1) ? py : pz);
            float a = ldexpf(c, l);
            v = (r < 3) ? sinf(a) : cosf(a);
        }
        s_xp[lane] = v;
    }
    // posenc(d) -> tail of hv buffer
    if (lane < 27) {
        float v;
        if (lane < 3) {
            v = (lane == 0) ? dxv : ((lane == 1) ? dyv : dzv);
        } else {
            int k = lane - 3, l = k / 6, r = k % 6;
            float c = ((r % 3) == 0) ? dxv : (((r % 3) == 1) ? dyv : dzv);
            float a = ldexpf(c, l);
            v = (r < 3) ? sinf(a) : cosf(a);
        }
        s_hv[32 + lane] = v;
    }
    __syncthreads();

    // layer 1: (63 -> 32) + relu
    float a = halfsum_matvec(s_xp, 63, W1 + e * 2016, b1 + e * 32, lane);
    if (lane < 32) s_ha[lane] = fmaxf(a, 0.f);
    __syncthreads();

    // layer 2: (32 -> 32) + relu
    a = halfsum_matvec(s_ha, 32, W2 + e * 1024, b2 + e * 32, lane);
    if (lane < 32) s_hb[lane] = fmaxf(a, 0.f);
    __syncthreads();

    // sigma head: (32 -> 1)
    {
        float partial = (lane < 32) ? s_hb[lane] * Wsig[e * 32 + lane] : 0.f;
        float sig = wave_sum64(partial);
        if (lane == 0) out_sigma[pt] = sig + bsig[e];
    }

    // feat: (32 -> 32), NO relu -> hv[0:32]
    a = halfsum_matvec(s_hb, 32, Wf + e * 1024, bfc + e * 32, lane);
    if (lane < 32) s_hv[lane] = a;
    __syncthreads();

    // view layer: (59 -> 32) + relu
    a = halfsum_matvec(s_hv, 59, Wv + e * 1888, bv + e * 32, lane);
    if (lane < 32) s_ha[lane] = fmaxf(a, 0.f);
    __syncthreads();

    // rgb head: (32 -> 3)
#pragma unroll
    for (int o = 0; o < 3; ++o) {
        float pr = (lane < 32) ? s_ha[lane] * Wrgb[(e * 32 + lane) * 3 + o] : 0.f;
        float s = wave_sum64(pr);
        if (lane == 0)
            out_rgb[3 * pt + o] = s + brgb[e * 3 + o];
    }
}

extern "C" void kernel_launch(void* const* d_in, const int* in_sizes, int n_in,
                              void* d_out, int out_size, void* d_ws, size_t ws_size,
                              hipStream_t stream) {
    const float* pts      = (const float*)d_in[0];
    const float* viewdirs = (const float*)d_in[1];
    const float* W1   = (const float*)d_in[2];
    const float* b1   = (const float*)d_in[3];
    const float* W2   = (const float*)d_in[4];
    const float* b2   = (const float*)d_in[5];
    const float* Wf   = (const float*)d_in[6];
    const float* bfc  = (const float*)d_in[7];
    const float* Wsig = (const float*)d_in[8];
    const float* bsig = (const float*)d_in[9];
    const float* Wv   = (const float*)d_in[10];
    const float* bv   = (const float*)d_in[11];
    const float* Wrgb = (const float*)d_in[12];
    const float* brgb = (const float*)d_in[13];

    const int n = in_sizes[0] / 3;          // 65536 points
    const int n_rays = in_sizes[1] / 3;     // 1024 rays
    const int samples = n / n_rays;         // 64 samples/ray

    float* out_rgb = (float*)d_out;
    float* out_sigma = out_rgb + (size_t)n * 3;

    kilonerf_kernel<<<n / 4, 256, 0, stream>>>(pts, viewdirs, W1, b1, W2, b2, Wf, bfc,
                                               Wsig, bsig, Wv, bv, Wrgb, brgb,
                                               out_rgb, out_sigma, samples);
}

// Round 4
// 399.721 us; speedup vs baseline: 1.1539x; 1.1539x over previous
//
#include <hip/hip_runtime.h>
#include <hip/hip_bf16.h>

// KiloNeRF grouped tiny-MLP, expert-bucketed dispatch.
// Round-3 counters: FETCH_SIZE 716 MB vs 101.6 MB weight set -> L2-fill bound
// (VALUBusy 26%). Fix: bucket points by expert (hist + scan + scatter), then
// one block per expert stages the expert's 6212 weight floats into LDS once
// and runs its ~16 points through the pipeline with LDS-resident weights.
//
// fp32 in / fp32 out (established rounds 1-3). Expert-index arithmetic
// mirrors the reference's float32 op order EXACTLY.

#define NPTS_BLK 256

// ---- workspace layout (ints) ----
// [0,4096)            counts
// [4096,8192)         offsets
// [8192,12288)        cursor
// [12288,12288+n)     order (point ids grouped by expert)
#define WS_COUNTS 0
#define WS_OFFSETS 4096
#define WS_CURSOR 8192
#define WS_ORDER 12288

// LDS weight-slab offsets (floats)
#define OFF_W1 0
#define OFF_B1 2016
#define OFF_W2 2048
#define OFF_B2 3072
#define OFF_WF 3104
#define OFF_BF 4128
#define OFF_WSIG 4160
#define OFF_BSIG 4192
#define OFF_WV 4224
#define OFF_BV 6112
#define OFF_WRGB 6144
#define OFF_BRGB 6240
#define LW_TOTAL 6272

__device__ __forceinline__ int expert_id(float px, float py, float pz) {
    // EXACT float32 op order of the reference
    float nx = (px - (-1.5f)) / 3.0f;
    float ny = (py - (-1.5f)) / 3.0f;
    float nz = (pz - (-1.5f)) / 3.0f;
    float sx = fminf(fmaxf(nx * 16.0f, 0.0f), 15.0f);
    float sy = fminf(fmaxf(ny * 16.0f, 0.0f), 15.0f);
    float sz = fminf(fmaxf(nz * 16.0f, 0.0f), 15.0f);
    return (int)sx * 256 + (int)sy * 16 + (int)sz;
}

__device__ __forceinline__ float wave_sum64(float v) {
#pragma unroll
    for (int off = 32; off >= 1; off >>= 1) v += __shfl_xor(v, off, 64);
    return v;
}

// out[o] = bias[o] + sum_i s_in[i] * W[i*32+o]; W,b in LDS, row-major (n x 32).
// Half-split over i: each ds_read hits rows i (half0) and i+1 (half1) -> banks
// 0..31 with 2-way aliasing (free per m136).
__device__ __forceinline__ float halfsum_matvec(const float* __restrict__ s_in, int n,
                                                const float* __restrict__ Wm,
                                                const float* __restrict__ bb,
                                                int lane) {
    const int half = lane >> 5;
    const int o = lane & 31;
    float acc = 0.f;
    for (int i = half; i < n; i += 2)
        acc = fmaf(s_in[i], Wm[i * 32 + o], acc);
    acc += __shfl_xor(acc, 32, 64);
    return acc + bb[o];
}

__device__ __forceinline__ void coop_copy(float* dst, const float* __restrict__ src,
                                          int n, int tid) {
    for (int i = tid; i < n; i += NPTS_BLK) dst[i] = src[i];
}

// ---------------- pass A: histogram ----------------
__global__ __launch_bounds__(256) void hist_kernel(const float* __restrict__ pts,
                                                   int* __restrict__ counts, int n) {
    int i = blockIdx.x * 256 + threadIdx.x;
    if (i < n) {
        int e = expert_id(pts[3 * i + 0], pts[3 * i + 1], pts[3 * i + 2]);
        atomicAdd(&counts[e], 1);
    }
}

// ---------------- pass B: exclusive scan of 4096 counts (1 block) ----------
__global__ __launch_bounds__(256) void scan_kernel(const int* __restrict__ counts,
                                                   int* __restrict__ offsets,
                                                   int* __restrict__ cursor) {
    const int tid = threadIdx.x;          // 0..255, 16 experts each
    const int lane = tid & 63, wave = tid >> 6;
    const int base = tid * 16;
    int c[16], loc[16], sum = 0;
#pragma unroll
    for (int j = 0; j < 16; ++j) c[j] = counts[base + j];
#pragma unroll
    for (int j = 0; j < 16; ++j) { loc[j] = sum; sum += c[j]; }
    // inclusive wave scan of per-thread totals
    int v = sum;
#pragma unroll
    for (int off = 1; off <= 32; off <<= 1) {
        int u = __shfl_up(v, off, 64);
        if (lane >= off) v += u;
    }
    __shared__ int wtot[4];
    if (lane == 63) wtot[wave] = v;
    __syncthreads();
    int wbase = 0;
    for (int w = 0; w < wave; ++w) wbase += wtot[w];
    const int excl = wbase + v - sum;
#pragma unroll
    for (int j = 0; j < 16; ++j) {
        int o = excl + loc[j];
        offsets[base + j] = o;
        cursor[base + j] = o;
    }
}

// ---------------- pass C: scatter point ids into buckets ----------------
__global__ __launch_bounds__(256) void scatter_kernel(const float* __restrict__ pts,
                                                      int* __restrict__ cursor,
                                                      int* __restrict__ order, int n) {
    int i = blockIdx.x * 256 + threadIdx.x;
    if (i < n) {
        int e = expert_id(pts[3 * i + 0], pts[3 * i + 1], pts[3 * i + 2]);
        int pos = atomicAdd(&cursor[e], 1);
        order[pos] = i;
    }
}

// ---------------- pass D: one block per expert ----------------
__global__ __launch_bounds__(NPTS_BLK) void expert_mlp_kernel(
    const float* __restrict__ pts, const float* __restrict__ viewdirs,
    const float* __restrict__ W1, const float* __restrict__ b1,
    const float* __restrict__ W2, const float* __restrict__ b2,
    const float* __restrict__ Wf, const float* __restrict__ bfc,
    const float* __restrict__ Wsig, const float* __restrict__ bsig,
    const float* __restrict__ Wv, const float* __restrict__ bv,
    const float* __restrict__ Wrgb, const float* __restrict__ brgb,
    const int* __restrict__ counts, const int* __restrict__ offsets,
    const int* __restrict__ order,
    float* __restrict__ out_rgb, float* __restrict__ out_sigma, int samples) {
    const int e = blockIdx.x;
    const int cnt = counts[e];
    if (cnt == 0) return;
    const int start = offsets[e];
    const int tid = threadIdx.x;
    const int wave = tid >> 6, lane = tid & 63;

    __shared__ float lw[LW_TOTAL];
    coop_copy(lw + OFF_W1, W1 + e * 2016, 2016, tid);
    coop_copy(lw + OFF_B1, b1 + e * 32, 32, tid);
    coop_copy(lw + OFF_W2, W2 + e * 1024, 1024, tid);
    coop_copy(lw + OFF_B2, b2 + e * 32, 32, tid);
    coop_copy(lw + OFF_WF, Wf + e * 1024, 1024, tid);
    coop_copy(lw + OFF_BF, bfc + e * 32, 32, tid);
    coop_copy(lw + OFF_WSIG, Wsig + e * 32, 32, tid);
    if (tid == 0) lw[OFF_BSIG] = bsig[e];
    coop_copy(lw + OFF_WV, Wv + e * 1888, 1888, tid);
    coop_copy(lw + OFF_BV, bv + e * 32, 32, tid);
    coop_copy(lw + OFF_WRGB, Wrgb + e * 96, 96, tid);
    coop_copy(lw + OFF_BRGB, brgb + e * 3, 3, tid);

    __shared__ float s_xp_all[4][63];
    __shared__ float s_ha_all[4][32];
    __shared__ float s_hb_all[4][32];
    __shared__ float s_hv_all[4][59];
    float* s_xp = s_xp_all[wave];
    float* s_ha = s_ha_all[wave];
    float* s_hb = s_hb_all[wave];
    float* s_hv = s_hv_all[wave];

    __syncthreads();

    const int iters = (cnt + 3) >> 2;   // all waves run same trip count (barriers)
    for (int it = 0; it < iters; ++it) {
        const int s = it * 4 + wave;
        const bool active = s < cnt;
        const int pt = order[start + (active ? s : 0)];

        const float px = pts[3 * pt + 0];
        const float py = pts[3 * pt + 1];
        const float pz = pts[3 * pt + 2];
        const int ray = pt / samples;
        const float dxv = viewdirs[3 * ray + 0];
        const float dyv = viewdirs[3 * ray + 1];
        const float dzv = viewdirs[3 * ray + 2];

        if (lane < 63) {
            float v;
            if (lane < 3) {
                v = (lane == 0) ? px : ((lane == 1) ? py : pz);
            } else {
                int k = lane - 3, l = k / 6, r = k % 6;
                float c = ((r % 3) == 0) ? px : (((r % 3) == 1) ? py : pz);
                float a = ldexpf(c, l);
                v = (r < 3) ? sinf(a) : cosf(a);
            }
            s_xp[lane] = v;
        }
        if (lane < 27) {
            float v;
            if (lane < 3) {
                v = (lane == 0) ? dxv : ((lane == 1) ? dyv : dzv);
            } else {
                int k = lane - 3, l = k / 6, r = k % 6;
                float c = ((r % 3) == 0) ? dxv : (((r % 3) == 1) ? dyv : dzv);
                float a = ldexpf(c, l);
                v = (r < 3) ? sinf(a) : cosf(a);
            }
            s_hv[32 + lane] = v;
        }
        __syncthreads();

        // layer 1: (63 -> 32) + relu
        float a = halfsum_matvec(s_xp, 63, lw + OFF_W1, lw + OFF_B1, lane);
        if (lane < 32) s_ha[lane] = fmaxf(a, 0.f);
        __syncthreads();

        // layer 2: (32 -> 32) + relu
        a = halfsum_matvec(s_ha, 32, lw + OFF_W2, lw + OFF_B2, lane);
        if (lane < 32) s_hb[lane] = fmaxf(a, 0.f);
        __syncthreads();

        // sigma head: (32 -> 1)
        {
            float partial = (lane < 32) ? s_hb[lane] * lw[OFF_WSIG + lane] : 0.f;
            float sig = wave_sum64(partial);
            if (lane == 0 && active) out_sigma[pt] = sig + lw[OFF_BSIG];
        }

        // feat: (32 -> 32), NO relu -> hv[0:32]
        a = halfsum_matvec(s_hb, 32, lw + OFF_WF, lw + OFF_BF, lane);
        if (lane < 32) s_hv[lane] = a;
        __syncthreads();

        // view layer: (59 -> 32) + relu
        a = halfsum_matvec(s_hv, 59, lw + OFF_WV, lw + OFF_BV, lane);
        if (lane < 32) s_ha[lane] = fmaxf(a, 0.f);
        __syncthreads();

        // rgb head: (32 -> 3)
#pragma unroll
        for (int o = 0; o < 3; ++o) {
            float pr = (lane < 32) ? s_ha[lane] * lw[OFF_WRGB + lane * 3 + o] : 0.f;
            float sm = wave_sum64(pr);
            if (lane == 0 && active) out_rgb[3 * pt + o] = sm + lw[OFF_BRGB + o];
        }
        __syncthreads();   // protect scratch before next iteration's posenc writes
    }
}

// ---------------- fallback: round-3 monolithic kernel ----------------
__global__ __launch_bounds__(256) void kilonerf_fallback(
    const float* __restrict__ pts, const float* __restrict__ viewdirs,
    const float* __restrict__ W1, const float* __restrict__ b1,
    const float* __restrict__ W2, const float* __restrict__ b2,
    const float* __restrict__ Wf, const float* __restrict__ bfc,
    const float* __restrict__ Wsig, const float* __restrict__ bsig,
    const float* __restrict__ Wv, const float* __restrict__ bv,
    const float* __restrict__ Wrgb, const float* __restrict__ brgb,
    float* __restrict__ out_rgb, float* __restrict__ out_sigma, int samples) {
    const int wave = threadIdx.x >> 6;
    const int lane = threadIdx.x & 63;
    const int pt = blockIdx.x * 4 + wave;

    __shared__ float s_xp_all[4][63];
    __shared__ float s_ha_all[4][32];
    __shared__ float s_hb_all[4][32];
    __shared__ float s_hv_all[4][59];
    float* s_xp = s_xp_all[wave];
    float* s_ha = s_ha_all[wave];
    float* s_hb = s_hb_all[wave];
    float* s_hv = s_hv_all[wave];

    const float px = pts[3 * pt + 0];
    const float py = pts[3 * pt + 1];
    const float pz = pts[3 * pt + 2];
    const int ray = pt / samples;
    const float dxv = viewdirs[3 * ray + 0];
    const float dyv = viewdirs[3 * ray + 1];
    const float dzv = viewdirs[3 * ray + 2];
    const int e = expert_id(px, py, pz);

    if (lane < 63) {
        float v;
        if (lane < 3) v = (lane == 0) ? px : ((lane == 1) ? py : pz);
        else {
            int k = lane - 3, l = k / 6, r = k % 6;
            float c = ((r % 3) == 0) ? px : (((r % 3) == 1) ? py : pz);
            float a2 = ldexpf(c, l);
            v = (r < 3) ? sinf(a2) : cosf(a2);
        }
        s_xp[lane] = v;
    }
    if (lane < 27) {
        float v;
        if (lane < 3) v = (lane == 0) ? dxv : ((lane == 1) ? dyv : dzv);
        else {
            int k = lane - 3, l = k / 6, r = k % 6;
            float c = ((r % 3) == 0) ? dxv : (((r % 3) == 1) ? dyv : dzv);
            float a2 = ldexpf(c, l);
            v = (r < 3) ? sinf(a2) : cosf(a2);
        }
        s_hv[32 + lane] = v;
    }
    __syncthreads();

    float a = halfsum_matvec(s_xp, 63, W1 + e * 2016, b1 + e * 32, lane);
    if (lane < 32) s_ha[lane] = fmaxf(a, 0.f);
    __syncthreads();
    a = halfsum_matvec(s_ha, 32, W2 + e * 1024, b2 + e * 32, lane);
    if (lane < 32) s_hb[lane] = fmaxf(a, 0.f);
    __syncthreads();
    {
        float partial = (lane < 32) ? s_hb[lane] * Wsig[e * 32 + lane] : 0.f;
        float sig = wave_sum64(partial);
        if (lane == 0) out_sigma[pt] = sig + bsig[e];
    }
    a = halfsum_matvec(s_hb, 32, Wf + e * 1024, bfc + e * 32, lane);
    if (lane < 32) s_hv[lane] = a;
    __syncthreads();
    a = halfsum_matvec(s_hv, 59, Wv + e * 1888, bv + e * 32, lane);
    if (lane < 32) s_ha[lane] = fmaxf(a, 0.f);
    __syncthreads();
#pragma unroll
    for (int o = 0; o < 3; ++o) {
        float pr = (lane < 32) ? s_ha[lane] * Wrgb[(e * 32 + lane) * 3 + o] : 0.f;
        float sm = wave_sum64(pr);
        if (lane == 0) out_rgb[3 * pt + o] = sm + brgb[e * 3 + o];
    }
}

extern "C" void kernel_launch(void* const* d_in, const int* in_sizes, int n_in,
                              void* d_out, int out_size, void* d_ws, size_t ws_size,
                              hipStream_t stream) {
    const float* pts      = (const float*)d_in[0];
    const float* viewdirs = (const float*)d_in[1];
    const float* W1   = (const float*)d_in[2];
    const float* b1   = (const float*)d_in[3];
    const float* W2   = (const float*)d_in[4];
    const float* b2   = (const float*)d_in[5];
    const float* Wf   = (const float*)d_in[6];
    const float* bfc  = (const float*)d_in[7];
    const float* Wsig = (const float*)d_in[8];
    const float* bsig = (const float*)d_in[9];
    const float* Wv   = (const float*)d_in[10];
    const float* bv   = (const float*)d_in[11];
    const float* Wrgb = (const float*)d_in[12];
    const float* brgb = (const float*)d_in[13];

    const int n = in_sizes[0] / 3;          // 65536 points
    const int n_rays = in_sizes[1] / 3;     // 1024 rays
    const int samples = n / n_rays;         // 64 samples/ray

    float* out_rgb = (float*)d_out;
    float* out_sigma = out_rgb + (size_t)n * 3;

    const size_t ws_needed = (size_t)(WS_ORDER + n) * sizeof(int);
    if (ws_size < ws_needed) {
        kilonerf_fallback<<<n / 4, 256, 0, stream>>>(
            pts, viewdirs, W1, b1, W2, b2, Wf, bfc, Wsig, bsig, Wv, bv, Wrgb, brgb,
            out_rgb, out_sigma, samples);
        return;
    }

    int* ws = (int*)d_ws;
    int* counts = ws + WS_COUNTS;
    int* offsets = ws + WS_OFFSETS;
    int* cursor = ws + WS_CURSOR;
    int* order = ws + WS_ORDER;

    hipMemsetAsync(counts, 0, 4096 * sizeof(int), stream);
    hist_kernel<<<n / 256, 256, 0, stream>>>(pts, counts, n);
    scan_kernel<<<1, 256, 0, stream>>>(counts, offsets, cursor);
    scatter_kernel<<<n / 256, 256, 0, stream>>>(pts, cursor, order, n);
    expert_mlp_kernel<<<4096, NPTS_BLK, 0, stream>>>(
        pts, viewdirs, W1, b1, W2, b2, Wf, bfc, Wsig, bsig, Wv, bv, Wrgb, brgb,
        counts, offsets, order, out_rgb, out_sigma, samples);
}

// Round 5
// 304.394 us; speedup vs baseline: 1.5153x; 1.3132x over previous
//
#include <hip/hip_runtime.h>
#include <hip/hip_bf16.h>

// KiloNeRF grouped tiny-MLP, expert-bucketed, barrier-free waves.
// Round-4 counters: FETCH fixed (53 MB) but VALUBusy 30% / occupancy 28% ->
// barrier+latency bound (7 syncthreads per point-iteration over 4 waves).
// Round-5: block = expert, weights staged TRANSPOSED in LDS (padded strides,
// ds_read_b128), each wave processes its own points independently -- the only
// __syncthreads is after weight staging. Activations live in registers +
// wave-private LDS scratch (same-wave DS ordering is program order).
//
// fp32 in / fp32 out. Expert-index arithmetic mirrors the reference's float32
// op order EXACTLY ((p+1.5f)/3.0f, *16, clip, trunc).

#define NPTS_BLK 256

// ---- workspace layout (ints) ----
#define WS_COUNTS 0
#define WS_OFFSETS 4096
#define WS_CURSOR 8192
#define WS_ORDER 12288

// ---- LDS weight slab (floats), transposed, padded strides ----
// 64-pad layers use row stride 68, 32-wide layers stride 36 (both keep 16B
// alignment; bank pattern (4o+i)%32 gives the b128 8-access/bank minimum).
#define L_W1T   0        // 32 rows x 68  (63 real cols, col 63 zeroed)
#define L_WVT   2176     // 32 rows x 68  (59 real cols, 59..63 zeroed)
#define L_W2T   4352     // 32 rows x 36
#define L_WFT   5504     // 32 rows x 36
#define L_WRGBT 6656     // 3 rows x 36
#define L_WSIG  6764     // 32
#define L_B1    6796
#define L_B2    6828
#define L_BF    6860
#define L_BV    6892
#define L_BSIG  6924
#define L_BRGB  6925
#define L_TOTAL 6928     // 27712 B

// per-wave IO scratch (floats, 16B-aligned chunks)
#define IO_XP 0          // 64 (63 real, [63] zeroed)
#define IO_HV 64         // 64 (feat 0..31 | xd 32..58 | 59..63 zeroed)
#define IO_H1 128        // 32
#define IO_H2 160        // 32
#define IO_PER_WAVE 192

__device__ __forceinline__ int expert_id(float px, float py, float pz) {
    float nx = (px - (-1.5f)) / 3.0f;
    float ny = (py - (-1.5f)) / 3.0f;
    float nz = (pz - (-1.5f)) / 3.0f;
    float sx = fminf(fmaxf(nx * 16.0f, 0.0f), 15.0f);
    float sy = fminf(fmaxf(ny * 16.0f, 0.0f), 15.0f);
    float sz = fminf(fmaxf(nz * 16.0f, 0.0f), 15.0f);
    return (int)sx * 256 + (int)sy * 16 + (int)sz;
}

// sum within each 32-lane half; every lane of the half gets the result
__device__ __forceinline__ float ws32(float v) {
#pragma unroll
    for (int off = 16; off >= 1; off >>= 1) v += __shfl_xor(v, off, 64);
    return v;
}

// acc_half = sum over this half's i-slices of s_in[i]*W_t[o][i].
// lane=(o,half); halves interleave 4-wide i-slices (0-3 / 4-7 / 8-11 ...).
template <int NPAD, int SW>
__device__ __forceinline__ float matvec_t(const float* s_in, const float* wt,
                                          int o, int half) {
    const float* wrow = wt + o * SW;
    float a0 = 0.f, a1 = 0.f;
#pragma unroll
    for (int i = half * 4; i < NPAD; i += 8) {
        float4 s4 = *(const float4*)(s_in + i);
        float4 w4 = *(const float4*)(wrow + i);
        a0 = fmaf(s4.x, w4.x, a0);
        a1 = fmaf(s4.y, w4.y, a1);
        a0 = fmaf(s4.z, w4.z, a0);
        a1 = fmaf(s4.w, w4.w, a1);
    }
    return a0 + a1;
}

// ---------------- pass A: histogram ----------------
__global__ __launch_bounds__(256) void hist_kernel(const float* __restrict__ pts,
                                                   int* __restrict__ counts, int n) {
    int i = blockIdx.x * 256 + threadIdx.x;
    if (i < n) {
        int e = expert_id(pts[3 * i + 0], pts[3 * i + 1], pts[3 * i + 2]);
        atomicAdd(&counts[e], 1);
    }
}

// ---------------- pass B: exclusive scan of 4096 counts (1 block) ----------
__global__ __launch_bounds__(256) void scan_kernel(const int* __restrict__ counts,
                                                   int* __restrict__ offsets,
                                                   int* __restrict__ cursor) {
    const int tid = threadIdx.x;
    const int lane = tid & 63, wave = tid >> 6;
    const int base = tid * 16;
    int c[16], loc[16], sum = 0;
#pragma unroll
    for (int j = 0; j < 16; ++j) c[j] = counts[base + j];
#pragma unroll
    for (int j = 0; j < 16; ++j) { loc[j] = sum; sum += c[j]; }
    int v = sum;
#pragma unroll
    for (int off = 1; off <= 32; off <<= 1) {
        int u = __shfl_up(v, off, 64);
        if (lane >= off) v += u;
    }
    __shared__ int wtot[4];
    if (lane == 63) wtot[wave] = v;
    __syncthreads();
    int wbase = 0;
    for (int w = 0; w < wave; ++w) wbase += wtot[w];
    const int excl = wbase + v - sum;
#pragma unroll
    for (int j = 0; j < 16; ++j) {
        int o = excl + loc[j];
        offsets[base + j] = o;
        cursor[base + j] = o;
    }
}

// ---------------- pass C: scatter point ids into buckets ----------------
__global__ __launch_bounds__(256) void scatter_kernel(const float* __restrict__ pts,
                                                      int* __restrict__ cursor,
                                                      int* __restrict__ order, int n) {
    int i = blockIdx.x * 256 + threadIdx.x;
    if (i < n) {
        int e = expert_id(pts[3 * i + 0], pts[3 * i + 1], pts[3 * i + 2]);
        int pos = atomicAdd(&cursor[e], 1);
        order[pos] = i;
    }
}

// ---------------- pass D: one block per expert, barrier-free waves --------
__global__ __launch_bounds__(NPTS_BLK) void expert_mlp_kernel(
    const float* __restrict__ pts, const float* __restrict__ viewdirs,
    const float* __restrict__ W1, const float* __restrict__ b1,
    const float* __restrict__ W2, const float* __restrict__ b2,
    const float* __restrict__ Wf, const float* __restrict__ bfc,
    const float* __restrict__ Wsig, const float* __restrict__ bsig,
    const float* __restrict__ Wv, const float* __restrict__ bv,
    const float* __restrict__ Wrgb, const float* __restrict__ brgb,
    const int* __restrict__ counts, const int* __restrict__ offsets,
    const int* __restrict__ order,
    float* __restrict__ out_rgb, float* __restrict__ out_sigma, int samples) {
    const int e = blockIdx.x;
    const int cnt = counts[e];
    if (cnt == 0) return;
    const int start = offsets[e];
    const int tid = threadIdx.x;
    const int wave = tid >> 6, lane = tid & 63;
    const int o = lane & 31, half = lane >> 5;

    __shared__ __align__(16) float lw[L_TOTAL];
    __shared__ __align__(16) float io[4 * IO_PER_WAVE];
    float* my = io + wave * IO_PER_WAVE;

    // ---- stage weights (zero first so the padded cols are 0) ----
    for (int t = tid; t < L_TOTAL; t += NPTS_BLK) lw[t] = 0.f;
    __syncthreads();
    for (int t = tid; t < 2016; t += NPTS_BLK) {
        int i = t >> 5, c = t & 31;
        lw[L_W1T + c * 68 + i] = W1[e * 2016 + t];
    }
    for (int t = tid; t < 1888; t += NPTS_BLK) {
        int i = t >> 5, c = t & 31;
        lw[L_WVT + c * 68 + i] = Wv[e * 1888 + t];
    }
    for (int t = tid; t < 1024; t += NPTS_BLK) {
        int i = t >> 5, c = t & 31;
        lw[L_W2T + c * 36 + i] = W2[e * 1024 + t];
        lw[L_WFT + c * 36 + i] = Wf[e * 1024 + t];
    }
    if (tid < 96) { int i = tid / 3, c = tid % 3; lw[L_WRGBT + c * 36 + i] = Wrgb[e * 96 + tid]; }
    if (tid < 32) {
        lw[L_WSIG + tid] = Wsig[e * 32 + tid];
        lw[L_B1 + tid] = b1[e * 32 + tid];
        lw[L_B2 + tid] = b2[e * 32 + tid];
        lw[L_BF + tid] = bfc[e * 32 + tid];
        lw[L_BV + tid] = bv[e * 32 + tid];
    }
    if (tid == 0) lw[L_BSIG] = bsig[e];
    if (tid < 3) lw[L_BRGB + tid] = brgb[e * 3 + tid];
    // zero the per-wave IO pads (stay zero forever; wave-private)
    if (lane == 63) my[IO_XP + 63] = 0.f;
    if (lane >= 59) my[IO_HV + lane] = 0.f;
    __syncthreads();   // the ONLY cross-wave barrier

    // ---- each wave streams its points independently ----
    for (int s = wave; s < cnt; s += 4) {
        const int pt = order[start + s];
        const float px = pts[3 * pt + 0];
        const float py = pts[3 * pt + 1];
        const float pz = pts[3 * pt + 2];
        const int ray = pt / samples;
        const float dxv = viewdirs[3 * ray + 0];
        const float dyv = viewdirs[3 * ray + 1];
        const float dzv = viewdirs[3 * ray + 2];

        // posenc(p) -> my[IO_XP + 0..62]
        if (lane < 63) {
            float v;
            if (lane < 3) {
                v = (lane == 0) ? px : ((lane == 1) ? py : pz);
            } else {
                int k = lane - 3, l = k / 6, r = k % 6;
                float c = ((r % 3) == 0) ? px : (((r % 3) == 1) ? py : pz);
                float a = ldexpf(c, l);
                v = (r < 3) ? sinf(a) : cosf(a);
            }
            my[IO_XP + lane] = v;
        }
        // posenc(d) -> my[IO_HV + 32..58]
        if (lane < 27) {
            float v;
            if (lane < 3) {
                v = (lane == 0) ? dxv : ((lane == 1) ? dyv : dzv);
            } else {
                int k = lane - 3, l = k / 6, r = k % 6;
                float c = ((r % 3) == 0) ? dxv : (((r % 3) == 1) ? dyv : dzv);
                float a = ldexpf(c, l);
                v = (r < 3) ? sinf(a) : cosf(a);
            }
            my[IO_HV + 32 + lane] = v;
        }

        // layer 1: (63 -> 32) + relu
        float acc = matvec_t<64, 68>(my + IO_XP, lw + L_W1T, o, half);
        acc += __shfl_xor(acc, 32, 64);
        float h1 = fmaxf(acc + lw[L_B1 + o], 0.f);
        if (lane < 32) my[IO_H1 + lane] = h1;

        // layer 2: (32 -> 32) + relu
        acc = matvec_t<32, 36>(my + IO_H1, lw + L_W2T, o, half);
        acc += __shfl_xor(acc, 32, 64);
        float h2 = fmaxf(acc + lw[L_B2 + o], 0.f);
        if (lane < 32) my[IO_H2 + lane] = h2;

        // sigma head (dot over 32; both halves hold identical h2 -> per-half sum)
        {
            float pr = h2 * lw[L_WSIG + o];
            pr = ws32(pr);
            if (lane == 0) out_sigma[pt] = pr + lw[L_BSIG];
        }

        // feat: (32 -> 32), no relu -> hv[0:32]
        acc = matvec_t<32, 36>(my + IO_H2, lw + L_WFT, o, half);
        acc += __shfl_xor(acc, 32, 64);
        float ft = acc + lw[L_BF + o];
        if (lane < 32) my[IO_HV + lane] = ft;

        // view layer: (59 -> 32) + relu (output stays in registers)
        acc = matvec_t<64, 68>(my + IO_HV, lw + L_WVT, o, half);
        acc += __shfl_xor(acc, 32, 64);
        float hv = fmaxf(acc + lw[L_BV + o], 0.f);

        // rgb head: 3 dots over 32
#pragma unroll
        for (int c = 0; c < 3; ++c) {
            float pr = hv * lw[L_WRGBT + c * 36 + o];
            pr = ws32(pr);
            if (lane == 0) out_rgb[3 * pt + c] = pr + lw[L_BRGB + c];
        }
    }
}

extern "C" void kernel_launch(void* const* d_in, const int* in_sizes, int n_in,
                              void* d_out, int out_size, void* d_ws, size_t ws_size,
                              hipStream_t stream) {
    const float* pts      = (const float*)d_in[0];
    const float* viewdirs = (const float*)d_in[1];
    const float* W1   = (const float*)d_in[2];
    const float* b1   = (const float*)d_in[3];
    const float* W2   = (const float*)d_in[4];
    const float* b2   = (const float*)d_in[5];
    const float* Wf   = (const float*)d_in[6];
    const float* bfc  = (const float*)d_in[7];
    const float* Wsig = (const float*)d_in[8];
    const float* bsig = (const float*)d_in[9];
    const float* Wv   = (const float*)d_in[10];
    const float* bv   = (const float*)d_in[11];
    const float* Wrgb = (const float*)d_in[12];
    const float* brgb = (const float*)d_in[13];

    const int n = in_sizes[0] / 3;          // 65536 points
    const int n_rays = in_sizes[1] / 3;     // 1024 rays
    const int samples = n / n_rays;         // 64 samples/ray

    float* out_rgb = (float*)d_out;
    float* out_sigma = out_rgb + (size_t)n * 3;

    int* ws = (int*)d_ws;
    int* counts = ws + WS_COUNTS;
    int* offsets = ws + WS_OFFSETS;
    int* cursor = ws + WS_CURSOR;
    int* order = ws + WS_ORDER;

    hipMemsetAsync(counts, 0, 4096 * sizeof(int), stream);
    hist_kernel<<<(n + 255) / 256, 256, 0, stream>>>(pts, counts, n);
    scan_kernel<<<1, 256, 0, stream>>>(counts, offsets, cursor);
    scatter_kernel<<<(n + 255) / 256, 256, 0, stream>>>(pts, cursor, order, n);
    expert_mlp_kernel<<<4096, NPTS_BLK, 0, stream>>>(
        pts, viewdirs, W1, b1, W2, b2, Wf, bfc, Wsig, bsig, Wv, bv, Wrgb, brgb,
        counts, offsets, order, out_rgb, out_sigma, samples);
}